// Round 2
// baseline (620.778 us; speedup 1.0000x reference)
//
#include <hip/hip_runtime.h>
#include <cfloat>
#include <math.h>

// Problem constants (z: [16,64,64,256] fp32, codebook: [1024,256] fp32)
#define P_TOT 65536
#define DIM   256
#define KTOT  1024
#define BETA_ 0.25f
#define EPS_  1e-5f

#define OUT_LOSS_OFF ((size_t)P_TOT * DIM)
#define OUT_IDX_OFF  (OUT_LOSS_OFF + 4)

// ---------------- pre: z2[p], e2[k], zero hist & loss_sum ------------------
// Arithmetic per pixel/row is IDENTICAL to round-1 kernels (bitwise frozen).
__global__ __launch_bounds__(256) void vq_pre(const float* __restrict__ z,
                                              const float* __restrict__ cb,
                                              float* __restrict__ z2,
                                              float* __restrict__ e2,
                                              unsigned int* __restrict__ hist,
                                              float* __restrict__ loss_sum) {
    const int lane = threadIdx.x & 63;
    const int wave = threadIdx.x >> 6;
    const int b = blockIdx.x;
    if (b < P_TOT / 4) {
        const int p = b * 4 + wave;
        float4 v = *(const float4*)(z + (size_t)p * DIM + lane * 4);
        float s = v.x * v.x + v.y * v.y + v.z * v.z + v.w * v.w;
        #pragma unroll
        for (int off = 32; off > 0; off >>= 1) s += __shfl_down(s, off, 64);
        if (lane == 0) z2[p] = s;
    } else {
        const int b2 = b - P_TOT / 4;          // 0..255
        const int k = b2 * 4 + wave;
        float4 v = *(const float4*)(cb + (size_t)k * DIM + lane * 4);
        float s = v.x * v.x + v.y * v.y + v.z * v.z + v.w * v.w;
        #pragma unroll
        for (int off = 32; off > 0; off >>= 1) s += __shfl_down(s, off, 64);
        if (lane == 0) e2[k] = s;
        if (b2 < 4) hist[b2 * 256 + threadIdx.x] = 0u;
        if (b2 == 0 && threadIdx.x == 0) *loss_sum = 0.0f;
    }
}

// ---------------- main: tiled fp32 GEMM-argmin + fused epilogue -------------
// BM=128 rows, BN=256 cols, BD=32 d-chunk. 256 threads, 8x16 acc/thread.
// LDS tiles are row-major with 36-float padded rows (cols 32..35 junk),
// filled lane-linearly by global_load_lds dwordx4 (9 granules/row, #8=pad).
#define BM 128
#define BN 256
#define BD 32
#define ROWF 36                       // padded row length in floats
#define A_GRAN (BM * 9)               // 1152 granules (16B each)
#define B_GRAN (BN * 9)               // 2304
#define TOT_GRAN (A_GRAN + B_GRAN)    // 3456
#define SMEM_F (TOT_GRAN * 4)         // 13824 floats = 55296 B

__global__ __launch_bounds__(256, 2) void vq_argmin(
    const float* __restrict__ z, const float* __restrict__ cb,
    const float* __restrict__ z2, const float* __restrict__ e2,
    unsigned int* __restrict__ hist, float* __restrict__ loss_sum,
    float* __restrict__ out)
{
    __shared__ __align__(16) float smem[SMEM_F];
    __shared__ int   kwin[BM];
    __shared__ float wred[4];
    float* As = smem;                 // [128][36]
    float* Bs = smem + A_GRAN * 4;    // [256][36]
    // reduction overlay on smem (17.4 KB <= 55 KB)
    float* Rd = smem;                 // [128][17]
    int*   Ri = (int*)(smem + BM * 17);

    const int tid = threadIdx.x;
    const int tx = tid & 15;          // col group: cols tx + 16c
    const int ty = tid >> 4;          // row group: rows ty + 16r
    const int row0 = blockIdx.x * BM;

    float z2r[8];
    #pragma unroll
    for (int r = 0; r < 8; ++r) z2r[r] = z2[row0 + ty + 16 * r];

    float best[8]; int bidx[8];
    #pragma unroll
    for (int r = 0; r < 8; ++r) { best[r] = FLT_MAX; bidx[r] = 0; }

    #pragma unroll 1
    for (int kc = 0; kc < KTOT / BN; ++kc) {
        const int k0 = kc * BN;
        float acc[8][16];
        #pragma unroll
        for (int r = 0; r < 8; ++r)
            #pragma unroll
            for (int c = 0; c < 16; ++c) acc[r][c] = 0.0f;

        #pragma unroll 1
        for (int dc = 0; dc < DIM / BD; ++dc) {
            const float* zb  = z  + (size_t)row0 * DIM + dc * BD;
            const float* cbb = cb + (size_t)k0  * DIM + dc * BD;
            __syncthreads();
            #pragma unroll
            for (int i = 0; i < 14; ++i) {
                const int g = i * 256 + tid;
                if (g < A_GRAN) {
                    unsigned row = (unsigned)g / 9u;
                    unsigned c4  = (unsigned)g - row * 9u; if (c4 > 7u) c4 = 7u;
                    const float* gp = zb + row * DIM + c4 * 4;
                    __builtin_amdgcn_global_load_lds(
                        (const __attribute__((address_space(1))) void*)gp,
                        (__attribute__((address_space(3))) void*)&smem[g * 4], 16, 0, 0);
                } else if (g < TOT_GRAN) {
                    const int h = g - A_GRAN;
                    unsigned col = (unsigned)h / 9u;
                    unsigned c4  = (unsigned)h - col * 9u; if (c4 > 7u) c4 = 7u;
                    const float* gp = cbb + col * DIM + c4 * 4;
                    __builtin_amdgcn_global_load_lds(
                        (const __attribute__((address_space(1))) void*)gp,
                        (__attribute__((address_space(3))) void*)&smem[g * 4], 16, 0, 0);
                }
            }
            __syncthreads();

            #pragma unroll 2
            for (int g4 = 0; g4 < BD / 4; ++g4) {
                float a[8][4];
                #pragma unroll
                for (int r = 0; r < 8; ++r) {
                    float4 av = *(const float4*)&As[(ty + 16 * r) * ROWF + g4 * 4];
                    a[r][0] = av.x; a[r][1] = av.y; a[r][2] = av.z; a[r][3] = av.w;
                }
                #pragma unroll
                for (int ch = 0; ch < 2; ++ch) {
                    float bfr[8][4];
                    #pragma unroll
                    for (int c = 0; c < 8; ++c) {
                        float4 bv = *(const float4*)&Bs[(tx + 16 * (ch * 8 + c)) * ROWF + g4 * 4];
                        bfr[c][0] = bv.x; bfr[c][1] = bv.y; bfr[c][2] = bv.z; bfr[c][3] = bv.w;
                    }
                    // d strictly ascending per (p,k): j inner-sequential
                    #pragma unroll
                    for (int j = 0; j < 4; ++j)
                        #pragma unroll
                        for (int r = 0; r < 8; ++r)
                            #pragma unroll
                            for (int c = 0; c < 8; ++c)
                                acc[r][ch * 8 + c] =
                                    fmaf(a[r][j], bfr[c][j], acc[r][ch * 8 + c]);
                }
            }
        }
        // fold this k-chunk: dist = (z2 + e2[k]) - 2*ze, ref rounding.
        // k = k0 + tx + 16c ascends with (kc, c) -> strict < keeps lowest k.
        #pragma unroll
        for (int c = 0; c < 16; ++c) {
            const float ev = e2[k0 + tx + 16 * c];
            #pragma unroll
            for (int r = 0; r < 8; ++r) {
                float dist = (z2r[r] + ev) - 2.0f * acc[r][c];
                if (dist < best[r]) { best[r] = dist; bidx[r] = k0 + tx + 16 * c; }
            }
        }
    }

    // cross-thread (k-direction) reduction, tie -> smaller index
    __syncthreads();
    #pragma unroll
    for (int r = 0; r < 8; ++r) {
        Rd[(ty + 16 * r) * 17 + tx] = best[r];
        Ri[(ty + 16 * r) * 17 + tx] = bidx[r];
    }
    __syncthreads();
    if (tid < BM) {
        float bd = Rd[tid * 17]; int bi = Ri[tid * 17];
        #pragma unroll
        for (int t = 1; t < 16; ++t) {
            float dc_ = Rd[tid * 17 + t]; int ic = Ri[tid * 17 + t];
            if (dc_ < bd || (dc_ == bd && ic < bi)) { bd = dc_; bi = ic; }
        }
        kwin[tid] = bi;
        out[OUT_IDX_OFF + row0 + tid] = (float)bi;
        atomicAdd(&hist[bi], 1u);
    }
    __syncthreads();

    // epilogue: z_q_st = z + (z_q - z) (ref rounding) + loss partial
    float lacc = 0.0f;
    #pragma unroll 4
    for (int i = 0; i < 32; ++i) {
        const int flat4 = tid + i * 256;
        const int row = flat4 >> 6;            // wave-uniform
        const int dj = (flat4 & 63) * 4;
        const size_t zoff = (size_t)(row0 + row) * DIM + dj;
        float4 zv = *(const float4*)(z + zoff);
        float4 evv = *(const float4*)(cb + (size_t)kwin[row] * DIM + dj);
        float dx = evv.x - zv.x, dy = evv.y - zv.y, dz = evv.z - zv.z, dw = evv.w - zv.w;
        float4 o;
        o.x = zv.x + dx; o.y = zv.y + dy; o.z = zv.z + dz; o.w = zv.w + dw;
        *(float4*)(out + zoff) = o;
        lacc += dx * dx + dy * dy + dz * dz + dw * dw;
    }
    #pragma unroll
    for (int off = 32; off > 0; off >>= 1) lacc += __shfl_down(lacc, off, 64);
    const int lane = tid & 63, wid = tid >> 6;
    if (lane == 0) wred[wid] = lacc;
    __syncthreads();
    if (tid == 0) atomicAdd(loss_sum, wred[0] + wred[1] + wred[2] + wred[3]);
}

// ---------------- finalize: losses + perplexity -----------------------------
__global__ __launch_bounds__(1024) void vq_finalize(
    const unsigned int* __restrict__ hist, const float* __restrict__ loss_sum,
    float* __restrict__ out)
{
    __shared__ float sred[16];
    __shared__ float totalsh;
    const int tid = threadIdx.x;
    const float c = (float)hist[tid];

    float t = c;
    #pragma unroll
    for (int off = 32; off > 0; off >>= 1) t += __shfl_down(t, off, 64);
    if ((tid & 63) == 0) sred[tid >> 6] = t;
    __syncthreads();
    if (tid == 0) {
        float s = 0.0f;
        for (int i = 0; i < 16; ++i) s += sred[i];
        totalsh = s;
    }
    __syncthreads();
    const float total = totalsh;
    const float prob = c / (total + EPS_);
    float term = prob * logf(prob + EPS_);
    __syncthreads();
    #pragma unroll
    for (int off = 32; off > 0; off >>= 1) term += __shfl_down(term, off, 64);
    if ((tid & 63) == 0) sred[tid >> 6] = term;
    __syncthreads();
    if (tid == 0) {
        float s = 0.0f;
        for (int i = 0; i < 16; ++i) s += sred[i];
        const float perp = expf(-s);
        const float S = *loss_sum;
        const float mean = S / (float)(P_TOT * DIM);
        out[OUT_LOSS_OFF + 0] = mean;                  // commitment_loss
        out[OUT_LOSS_OFF + 1] = mean;                  // codebook_loss
        out[OUT_LOSS_OFF + 2] = mean + BETA_ * mean;   // cluster_loss
        out[OUT_LOSS_OFF + 3] = perp;                  // perplexity
    }
}

extern "C" void kernel_launch(void* const* d_in, const int* in_sizes, int n_in,
                              void* d_out, int out_size, void* d_ws, size_t ws_size,
                              hipStream_t stream) {
    const float* z  = (const float*)d_in[0];
    const float* cb = (const float*)d_in[1];
    float* out = (float*)d_out;

    float* z2 = (float*)d_ws;
    float* e2 = z2 + P_TOT;
    unsigned int* hist = (unsigned int*)(e2 + KTOT);
    float* loss_sum = (float*)(hist + KTOT);

    vq_pre<<<P_TOT / 4 + 256, 256, 0, stream>>>(z, cb, z2, e2, hist, loss_sum);
    vq_argmin<<<P_TOT / BM, 256, 0, stream>>>(z, cb, z2, e2, hist, loss_sum, out);
    vq_finalize<<<1, 1024, 0, stream>>>(hist, loss_sum, out);
}